// Round 3
// baseline (296.390 us; speedup 1.0000x reference)
//
#include <hip/hip_runtime.h>

#define NPTS_C 32            // channels
#define NTAPS 27             // 3x3x3
#define KEY_WORDS (1u << 20) // 2^25 keys / 32 bits
#define SCAN_BLOCKS 1024     // KEY_WORDS / 1024 words per block

typedef float f32x4 __attribute__((ext_vector_type(4))); // native vec for nontemporal store

__device__ __forceinline__ unsigned make_key(int b, int x, int y, int z) {
    return ((((unsigned)b << 8 | (unsigned)x) << 8 | (unsigned)y) << 8) | (unsigned)z;
}

// 1) scatter occupancy bits
__global__ void k_scatter_bits(const int4* __restrict__ coords, unsigned* __restrict__ bitmask, int n) {
    int i = blockIdx.x * blockDim.x + threadIdx.x;
    if (i >= n) return;
    int4 co = coords[i];
    unsigned key = make_key(co.x, co.y, co.z, co.w);
    atomicOr(&bitmask[key >> 5], 1u << (key & 31u));
}

// 2) per-block (1024 words) popcount sums
__global__ void k_popc_sums(const uint4* __restrict__ bm4, unsigned* __restrict__ blockSums) {
    int t = threadIdx.x;
    uint4 w = bm4[blockIdx.x * 256 + t];
    unsigned s = __popc(w.x) + __popc(w.y) + __popc(w.z) + __popc(w.w);
    for (int off = 32; off > 0; off >>= 1) s += __shfl_down(s, off, 64);
    __shared__ unsigned wsum[4];
    if ((t & 63) == 0) wsum[t >> 6] = s;
    __syncthreads();
    if (t == 0) blockSums[blockIdx.x] = wsum[0] + wsum[1] + wsum[2] + wsum[3];
}

// 3) combined[word] = {bits, exclusive prefix popcount}
__global__ void k_build_combined(const uint4* __restrict__ bm4, const unsigned* __restrict__ blockSums,
                                 uint4* __restrict__ combined4) {
    int t = threadIdx.x, lane = t & 63;
    __shared__ unsigned preW[4];
    __shared__ unsigned wsum[4];

    unsigned pre = 0;
    for (int i = t; i < blockIdx.x; i += 256) pre += blockSums[i];
    for (int off = 32; off > 0; off >>= 1) pre += __shfl_down(pre, off, 64);
    if (lane == 0) preW[t >> 6] = pre;
    __syncthreads();
    unsigned blockBase = preW[0] + preW[1] + preW[2] + preW[3];

    int gw = blockIdx.x * 256 + t;
    uint4 w = bm4[gw];
    unsigned p0 = __popc(w.x), p1 = __popc(w.y), p2 = __popc(w.z), p3 = __popc(w.w);
    unsigned s = p0 + p1 + p2 + p3;
    unsigned incl = s;
    for (int off = 1; off < 64; off <<= 1) {
        unsigned u = __shfl_up(incl, off, 64);
        if (lane >= off) incl += u;
    }
    if (lane == 63) wsum[t >> 6] = incl;
    __syncthreads();
    unsigned waveBase = 0;
    int wv = t >> 6;
    for (int i = 0; i < wv; i++) waveBase += wsum[i];
    unsigned excl = blockBase + waveBase + incl - s;
    uint4 a; a.x = w.x; a.y = excl;           a.z = w.y; a.w = excl + p0;
    uint4 b; b.x = w.z; b.y = excl + p0 + p1; b.z = w.w; b.w = excl + p0 + p1 + p2;
    combined4[gw * 2 + 0] = a;
    combined4[gw * 2 + 1] = b;
}

__device__ __forceinline__ unsigned rank_of(unsigned key, const uint2* __restrict__ combined) {
    uint2 cw = combined[key >> 5];
    unsigned bit = key & 31u;
    return cw.y + __popc(cw.x & ((1u << bit) - 1u));
}

// 4) origOf[rank] = original index (4 B scatter)
__global__ void k_scatter_rank(const int4* __restrict__ coords, const uint2* __restrict__ combined,
                               int* __restrict__ origOf, int n) {
    int i = blockIdx.x * blockDim.x + threadIdx.x;
    if (i >= n) return;
    int4 co = coords[i];
    unsigned r = rank_of(make_key(co.x, co.y, co.z, co.w), combined);
    origOf[r] = i;
}

// 5) FUSED conv, MLP version with REGISTERS: __launch_bounds__(256,2) gives the
//    allocator up to 256 VGPR/lane (8 waves/CU) so the 8-wide accumulate unroll
//    and the 4 resolve rounds actually keep their loads in flight.
//    (Round-2 lesson: at default bounds the compiler chose 32 VGPRs and
//    serialized every load -> MLP existed only in source, not in SASS.)
__global__ __launch_bounds__(256, 2) void k_conv_fused4(const float* __restrict__ feats,
                                                        const float* __restrict__ weight,
                                                        const int4* __restrict__ coords,
                                                        const uint2* __restrict__ combined,
                                                        const int* __restrict__ origOf,
                                                        float* __restrict__ out,
                                                        float* __restrict__ outCoordsF, int n) {
    __shared__ float4 swT4[28 * 9];                       // 28 taps (27 real + zero pad tap), pad 8->9
    __shared__ __attribute__((aligned(16))) int ldsL[8][4][28]; // [group][round][slot] packed nidx<<5|kk
    __shared__ int ldsCnt[8][4];                          // rounded-up (x4) list length

    int t = threadIdx.x;
    for (int idx = t; idx < 28 * 8; idx += 256) {
        int kk = idx >> 3, q = idx & 7;
        float4 w4;
        if (kk < NTAPS) {
            w4.x = weight[(4 * q + 0) * NTAPS + kk];
            w4.y = weight[(4 * q + 1) * NTAPS + kk];
            w4.z = weight[(4 * q + 2) * NTAPS + kk];
            w4.w = weight[(4 * q + 3) * NTAPS + kk];
        } else {
            w4.x = w4.y = w4.z = w4.w = 0.0f;             // dummy tap 27: zero weight
        }
        swT4[kk * 9 + q] = w4;
    }

    int gi = t >> 5, l = t & 31;
    bool hi = (t & 32) != 0;
    int p0 = (blockIdx.x * 8 + gi) * 4;  // 4 consecutive ranks per group
    int cluster = l >> 3, q = l & 7;

    // lane constants (hoisted out of the 4 resolve rounds)
    int dxl = l / 9 - 1, dyl = (l % 9) / 3 - 1, dzl = l % 3 - 1;
    int jl = l / 3;                      // probing lane for tap l
    int pbx = l / 3 - 1, pby = l % 3 - 1; // probe (dx,dy) for lanes 0..8

    #pragma unroll
    for (int r = 0; r < 4; r++) {
        int pc = min(p0 + r, n - 1);
        int o = origOf[pc];              // broadcast among 32 lanes
        int4 co = coords[o];             // broadcast scattered 16B read
        int cb = co.x, cx = co.y, cy = co.z, cz = co.w;

        if (l == 0 && p0 + r < n) {      // emit sorted coords (near-coalesced 16B stores)
            float4 fc; fc.x = (float)cb; fc.y = (float)cx; fc.z = (float)cy; fc.w = (float)cz;
            ((float4*)outCoordsF)[pc] = fc;
        }

        uint2 cw; cw.x = 0u; cw.y = 0u;
        if (l < 9) {
            int xj = cx + pbx, yj = cy + pby;
            if ((unsigned)xj < 256u && (unsigned)yj < 256u)
                cw = combined[make_key(cb, xj, yj, cz) >> 5];
        }
        unsigned bb = __shfl(cw.x, jl, 32);
        unsigned pp = __shfl(cw.y, jl, 32);

        int x = cx + dxl, y = cy + dyl, z = cz + dzl;
        int nidx = -1;
        if (l < NTAPS &&                 // center tap (l==13) included: resolves to self
            (unsigned)x < 256u && (unsigned)y < 256u && (unsigned)z < 256u) {
            unsigned keyk = make_key(cb, x, y, z);
            if ((z >> 5) != (cz >> 5)) { // z crossed word boundary: self-probe
                uint2 t2 = combined[keyk >> 5];
                bb = t2.x; pp = t2.y;
            }
            unsigned bit = keyk & 31u;
            if ((bb >> bit) & 1u)
                nidx = (int)(pp + __popc(bb & ((1u << bit) - 1u)));
        }
        // rank -> original index (parallel across tap lanes, overlapped across rounds)
        if (nidx >= 0) nidx = origOf[nidx]; // 4B read in 2.4MB L2-resident array

        unsigned long long bal = __ballot(nidx >= 0);
        unsigned mymask = hi ? (unsigned)(bal >> 32) : (unsigned)bal;
        unsigned pos = __popc(mymask & ((1u << l) - 1u));
        unsigned cnt = __popc(mymask);           // >= 1 (center always present)
        unsigned cnt4 = (cnt + 3u) & ~3u;
        if (nidx >= 0) ldsL[gi][r][pos] = (nidx << 5) | l;       // compacted write
        if (l == 0) ldsCnt[gi][r] = (int)cnt4;
        else if (l >= NTAPS && l < 31) {                         // lanes 27..30 write pads
            unsigned idx = cnt + (unsigned)(l - NTAPS);
            if (idx < cnt4) ldsL[gi][r][idx] = 27;               // nidx=0, tap 27 (w=0)
        }
    }
    __syncthreads(); // covers swT4 fill + ldsL/ldsCnt writes

    int pm = p0 + cluster;
    int cnt4 = ldsCnt[gi][cluster];
    const int* lst = &ldsL[gi][cluster][0];

    float4 a0, a1, a2, a3;
    a0.x=a0.y=a0.z=a0.w=0.0f; a1=a0; a2=a0; a3=a0;
    float4 b0, b1, b2, b3;
    b0 = a0; b1 = a0; b2 = a0; b3 = a0;

    int i = 0;
    for (; i + 8 <= cnt4; i += 8) {       // 8 scattered 128B rows in flight
        int4 va = *(const int4*)&lst[i];
        int4 vb = *(const int4*)&lst[i + 4];
        float4 f0 = ((const float4*)(feats + (size_t)(unsigned)(va.x >> 5) * NPTS_C))[q];
        float4 f1 = ((const float4*)(feats + (size_t)(unsigned)(va.y >> 5) * NPTS_C))[q];
        float4 f2 = ((const float4*)(feats + (size_t)(unsigned)(va.z >> 5) * NPTS_C))[q];
        float4 f3 = ((const float4*)(feats + (size_t)(unsigned)(va.w >> 5) * NPTS_C))[q];
        float4 f4 = ((const float4*)(feats + (size_t)(unsigned)(vb.x >> 5) * NPTS_C))[q];
        float4 f5 = ((const float4*)(feats + (size_t)(unsigned)(vb.y >> 5) * NPTS_C))[q];
        float4 f6 = ((const float4*)(feats + (size_t)(unsigned)(vb.z >> 5) * NPTS_C))[q];
        float4 f7 = ((const float4*)(feats + (size_t)(unsigned)(vb.w >> 5) * NPTS_C))[q];
        float4 w0 = swT4[(va.x & 31) * 9 + q];
        float4 w1 = swT4[(va.y & 31) * 9 + q];
        float4 w2 = swT4[(va.z & 31) * 9 + q];
        float4 w3 = swT4[(va.w & 31) * 9 + q];
        float4 w4 = swT4[(vb.x & 31) * 9 + q];
        float4 w5 = swT4[(vb.y & 31) * 9 + q];
        float4 w6 = swT4[(vb.z & 31) * 9 + q];
        float4 w7 = swT4[(vb.w & 31) * 9 + q];
        a0.x += f0.x * w0.x; a0.y += f0.y * w0.y; a0.z += f0.z * w0.z; a0.w += f0.w * w0.w;
        a1.x += f1.x * w1.x; a1.y += f1.y * w1.y; a1.z += f1.z * w1.z; a1.w += f1.w * w1.w;
        a2.x += f2.x * w2.x; a2.y += f2.y * w2.y; a2.z += f2.z * w2.z; a2.w += f2.w * w2.w;
        a3.x += f3.x * w3.x; a3.y += f3.y * w3.y; a3.z += f3.z * w3.z; a3.w += f3.w * w3.w;
        b0.x += f4.x * w4.x; b0.y += f4.y * w4.y; b0.z += f4.z * w4.z; b0.w += f4.w * w4.w;
        b1.x += f5.x * w5.x; b1.y += f5.y * w5.y; b1.z += f5.z * w5.z; b1.w += f5.w * w5.w;
        b2.x += f6.x * w6.x; b2.y += f6.y * w6.y; b2.z += f6.z * w6.z; b2.w += f6.w * w6.w;
        b3.x += f7.x * w7.x; b3.y += f7.y * w7.y; b3.z += f7.z * w7.z; b3.w += f7.w * w7.w;
    }
    if (i < cnt4) {                        // remainder is exactly one 4-group
        int4 v = *(const int4*)&lst[i];
        float4 f0 = ((const float4*)(feats + (size_t)(unsigned)(v.x >> 5) * NPTS_C))[q];
        float4 f1 = ((const float4*)(feats + (size_t)(unsigned)(v.y >> 5) * NPTS_C))[q];
        float4 f2 = ((const float4*)(feats + (size_t)(unsigned)(v.z >> 5) * NPTS_C))[q];
        float4 f3 = ((const float4*)(feats + (size_t)(unsigned)(v.w >> 5) * NPTS_C))[q];
        float4 w0 = swT4[(v.x & 31) * 9 + q];
        float4 w1 = swT4[(v.y & 31) * 9 + q];
        float4 w2 = swT4[(v.z & 31) * 9 + q];
        float4 w3 = swT4[(v.w & 31) * 9 + q];
        a0.x += f0.x * w0.x; a0.y += f0.y * w0.y; a0.z += f0.z * w0.z; a0.w += f0.w * w0.w;
        a1.x += f1.x * w1.x; a1.y += f1.y * w1.y; a1.z += f1.z * w1.z; a1.w += f1.w * w1.w;
        a2.x += f2.x * w2.x; a2.y += f2.y * w2.y; a2.z += f2.z * w2.z; a2.w += f2.w * w2.w;
        a3.x += f3.x * w3.x; a3.y += f3.y * w3.y; a3.z += f3.z * w3.z; a3.w += f3.w * w3.w;
    }
    if (pm < n) {
        f32x4 v;
        v.x = ((a0.x + a1.x) + (a2.x + a3.x)) + ((b0.x + b1.x) + (b2.x + b3.x));
        v.y = ((a0.y + a1.y) + (a2.y + a3.y)) + ((b0.y + b1.y) + (b2.y + b3.y));
        v.z = ((a0.z + a1.z) + (a2.z + a3.z)) + ((b0.z + b1.z) + (b2.z + b3.z));
        v.w = ((a0.w + a1.w) + (a2.w + a3.w)) + ((b0.w + b1.w) + (b2.w + b3.w));
        f32x4* dst = (f32x4*)(out + (size_t)pm * NPTS_C);
        __builtin_nontemporal_store(v, &dst[q]);
    }
}

extern "C" void kernel_launch(void* const* d_in, const int* in_sizes, int n_in,
                              void* d_out, int out_size, void* d_ws, size_t ws_size,
                              hipStream_t stream) {
    const float* feats  = (const float*)d_in[0];
    const int4*  coords = (const int4*)d_in[1];
    const float* weight = (const float*)d_in[2];
    const int n = in_sizes[1] / 4;

    float* out        = (float*)d_out;              // [N, 32] f32
    float* outCoordsF = (float*)d_out + n * NPTS_C; // [N, 4] float values

    char* ws = (char*)d_ws;
    unsigned* bitmask   = (unsigned*)ws;                               // 4 MB (reused as origOf)
    uint2*    combined  = (uint2*)(ws + (size_t)KEY_WORDS * 4);        // 8 MB
    unsigned* blockSums = (unsigned*)(ws + (size_t)KEY_WORDS * 12);    // 4 KB

    int* origOf = (int*)bitmask; // bitmask dead after k_build_combined; N*4 <= 4 MB

    (void)hipMemsetAsync(bitmask, 0, (size_t)KEY_WORDS * 4, stream);

    int tb = 256;
    k_scatter_bits<<<(n + tb - 1) / tb, tb, 0, stream>>>(coords, bitmask, n);
    k_popc_sums<<<SCAN_BLOCKS, 256, 0, stream>>>((const uint4*)bitmask, blockSums);
    k_build_combined<<<SCAN_BLOCKS, 256, 0, stream>>>((const uint4*)bitmask, blockSums, (uint4*)combined);
    k_scatter_rank<<<(n + tb - 1) / tb, tb, 0, stream>>>(coords, combined, origOf, n);
    k_conv_fused4<<<(n + 31) / 32, 256, 0, stream>>>(feats, weight, coords, combined, origOf,
                                                     out, outCoordsF, n);
}

// Round 4
// 248.307 us; speedup vs baseline: 1.1936x; 1.1936x over previous
//
#include <hip/hip_runtime.h>

#define NPTS_C 32            // channels
#define NTAPS 27             // 3x3x3
#define KEY_WORDS (1u << 20) // 2^25 keys / 32 bits
#define SCAN_BLOCKS 1024     // KEY_WORDS / 1024 words per block

typedef float f32x4 __attribute__((ext_vector_type(4))); // native vec for nontemporal store

__device__ __forceinline__ unsigned make_key(int b, int x, int y, int z) {
    return ((((unsigned)b << 8 | (unsigned)x) << 8 | (unsigned)y) << 8) | (unsigned)z;
}

// 1) scatter occupancy bits
__global__ void k_scatter_bits(const int4* __restrict__ coords, unsigned* __restrict__ bitmask, int n) {
    int i = blockIdx.x * blockDim.x + threadIdx.x;
    if (i >= n) return;
    int4 co = coords[i];
    unsigned key = make_key(co.x, co.y, co.z, co.w);
    atomicOr(&bitmask[key >> 5], 1u << (key & 31u));
}

// 2) per-block (1024 words) popcount sums
__global__ void k_popc_sums(const uint4* __restrict__ bm4, unsigned* __restrict__ blockSums) {
    int t = threadIdx.x;
    uint4 w = bm4[blockIdx.x * 256 + t];
    unsigned s = __popc(w.x) + __popc(w.y) + __popc(w.z) + __popc(w.w);
    for (int off = 32; off > 0; off >>= 1) s += __shfl_down(s, off, 64);
    __shared__ unsigned wsum[4];
    if ((t & 63) == 0) wsum[t >> 6] = s;
    __syncthreads();
    if (t == 0) blockSums[blockIdx.x] = wsum[0] + wsum[1] + wsum[2] + wsum[3];
}

// 3) combined[word] = {bits, exclusive prefix popcount}
__global__ void k_build_combined(const uint4* __restrict__ bm4, const unsigned* __restrict__ blockSums,
                                 uint4* __restrict__ combined4) {
    int t = threadIdx.x, lane = t & 63;
    __shared__ unsigned preW[4];
    __shared__ unsigned wsum[4];

    unsigned pre = 0;
    for (int i = t; i < blockIdx.x; i += 256) pre += blockSums[i];
    for (int off = 32; off > 0; off >>= 1) pre += __shfl_down(pre, off, 64);
    if (lane == 0) preW[t >> 6] = pre;
    __syncthreads();
    unsigned blockBase = preW[0] + preW[1] + preW[2] + preW[3];

    int gw = blockIdx.x * 256 + t;
    uint4 w = bm4[gw];
    unsigned p0 = __popc(w.x), p1 = __popc(w.y), p2 = __popc(w.z), p3 = __popc(w.w);
    unsigned s = p0 + p1 + p2 + p3;
    unsigned incl = s;
    for (int off = 1; off < 64; off <<= 1) {
        unsigned u = __shfl_up(incl, off, 64);
        if (lane >= off) incl += u;
    }
    if (lane == 63) wsum[t >> 6] = incl;
    __syncthreads();
    unsigned waveBase = 0;
    int wv = t >> 6;
    for (int i = 0; i < wv; i++) waveBase += wsum[i];
    unsigned excl = blockBase + waveBase + incl - s;
    uint4 a; a.x = w.x; a.y = excl;           a.z = w.y; a.w = excl + p0;
    uint4 b; b.x = w.z; b.y = excl + p0 + p1; b.z = w.w; b.w = excl + p0 + p1 + p2;
    combined4[gw * 2 + 0] = a;
    combined4[gw * 2 + 1] = b;
}

__device__ __forceinline__ unsigned rank_of(unsigned key, const uint2* __restrict__ combined) {
    uint2 cw = combined[key >> 5];
    unsigned bit = key & 31u;
    return cw.y + __popc(cw.x & ((1u << bit) - 1u));
}

// 4) FUSED rank+gather, scatter-WRITE version: read feats coalesced in original
//    order, write rows to sfeats[rank] (scattered 128B full-row writes — latency
//    tolerant, no RMW). Replaces k_scatter_rank + k_gather_sorted4 and removes
//    origOf from the hot path. (Round-3 lesson: scattered dependent READS can't
//    be pipelined by the compiler; scattered writes don't need to be.)
__global__ __launch_bounds__(256) void k_scatter_feats(const float* __restrict__ feats,
                                                       const int4* __restrict__ coords,
                                                       const uint2* __restrict__ combined,
                                                       float* __restrict__ sfeats,
                                                       float* __restrict__ outCoordsF, int n) {
    int t = blockIdx.x * 256 + threadIdx.x;
    int i = t >> 3, q = t & 7;
    if (i >= n) return;
    int4 co = coords[i];                                  // 8 lanes share one 16B line
    unsigned r = rank_of(make_key(co.x, co.y, co.z, co.w), combined);
    float4 f = ((const float4*)(feats + (size_t)i * NPTS_C))[q]; // fully coalesced read
    ((float4*)(sfeats + (size_t)r * NPTS_C))[q] = f;             // scattered full-row write
    if (q == 0) {
        float4 fc; fc.x = (float)co.x; fc.y = (float)co.y; fc.z = (float)co.z; fc.w = (float)co.w;
        ((float4*)outCoordsF)[r] = fc;                    // coords as float VALUES
    }
}

// 5) conv: 4 points per 32-group, center-tap split, float4 cluster gathers.
//    (verbatim round-0 kernel: 60 us verified; neighbor ranks hit rank-local
//    sfeats, L3-resident)
__global__ __launch_bounds__(256) void k_conv_sorted4(const float* __restrict__ sfeats,
                                                      const float* __restrict__ weight,
                                                      const float* __restrict__ outCoordsF,
                                                      const uint2* __restrict__ combined,
                                                      float* __restrict__ out, int n) {
    __shared__ float4 swT4[NTAPS * 9];   // swT4[kk*9+q] = weights for channels 4q..4q+3, tap kk (pad 8->9)
    __shared__ int ldsN[8][4][28];       // [group][round][tap] resolved sorted rank or -1

    int t = threadIdx.x;
    for (int idx = t; idx < NTAPS * 8; idx += 256) {
        int kk = idx >> 3, q = idx & 7;
        float4 w4;
        w4.x = weight[(4 * q + 0) * NTAPS + kk];
        w4.y = weight[(4 * q + 1) * NTAPS + kk];
        w4.z = weight[(4 * q + 2) * NTAPS + kk];
        w4.w = weight[(4 * q + 3) * NTAPS + kk];
        swT4[kk * 9 + q] = w4;
    }

    int gi = t >> 5, l = t & 31;
    bool hi = (t & 32) != 0;
    int p0 = (blockIdx.x * 8 + gi) * 4;  // 4 consecutive ranks per group
    int cluster = l >> 3, q = l & 7;

    // lane constants (hoisted out of the 4 resolve rounds)
    int dxl = l / 9 - 1, dyl = (l % 9) / 3 - 1, dzl = l % 3 - 1;
    int jl = l / 3;                      // probing lane for tap l
    int pbx = l / 3 - 1, pby = l % 3 - 1; // probe (dx,dy) for lanes 0..8

    unsigned mk[4];
    #pragma unroll
    for (int r = 0; r < 4; r++) {
        int pc = min(p0 + r, n - 1);
        float4 cf = ((const float4*)outCoordsF)[pc]; // broadcast; 4 rounds share one 64B line
        int cb = (int)cf.x, cx = (int)cf.y, cy = (int)cf.z, cz = (int)cf.w;

        uint2 cw; cw.x = 0u; cw.y = 0u;
        if (l < 9) {
            int xj = cx + pbx, yj = cy + pby;
            if ((unsigned)xj < 256u && (unsigned)yj < 256u)
                cw = combined[make_key(cb, xj, yj, cz) >> 5];
        }
        unsigned bb = __shfl(cw.x, jl, 32);
        unsigned pp = __shfl(cw.y, jl, 32);

        int x = cx + dxl, y = cy + dyl, z = cz + dzl;
        int nidx = -1;
        if (l < NTAPS && l != 13 &&
            (unsigned)x < 256u && (unsigned)y < 256u && (unsigned)z < 256u) {
            unsigned keyk = make_key(cb, x, y, z);
            if ((z >> 5) != (cz >> 5)) { // z crossed word boundary: self-probe
                uint2 t2 = combined[keyk >> 5];
                bb = t2.x; pp = t2.y;
            }
            unsigned bit = keyk & 31u;
            if ((bb >> bit) & 1u)
                nidx = (int)(pp + __popc(bb & ((1u << bit) - 1u)));
        }
        unsigned long long bal = __ballot(nidx >= 0);
        mk[r] = hi ? (unsigned)(bal >> 32) : (unsigned)bal;
        if (l < NTAPS) ldsN[gi][r][l] = nidx;
    }
    __syncthreads(); // covers swT4 fill + ldsN writes

    int pm = p0 + cluster;
    float4 acc; acc.x = acc.y = acc.z = acc.w = 0.0f;
    if (pm < n) { // center tap: coalesced row read (512B contiguous per group)
        float4 f = ((const float4*)(sfeats + (size_t)pm * NPTS_C))[q];
        float4 w4 = swT4[13 * 9 + q];
        acc.x = f.x * w4.x; acc.y = f.y * w4.y; acc.z = f.z * w4.z; acc.w = f.w * w4.w;
    }

    unsigned m = mk[cluster]; // cluster-uniform mask, ~0.47 set bits avg
    while (m) {
        int kk = __ffs(m) - 1; m &= m - 1;
        int g = ldsN[gi][cluster][kk];                        // broadcast ds_read
        float4 f = ((const float4*)(sfeats + (size_t)g * NPTS_C))[q]; // rank-local 128B row
        float4 w4 = swT4[kk * 9 + q];
        acc.x += f.x * w4.x; acc.y += f.y * w4.y; acc.z += f.z * w4.z; acc.w += f.w * w4.w;
    }
    if (pm < n) {
        f32x4 v; v.x = acc.x; v.y = acc.y; v.z = acc.z; v.w = acc.w;
        f32x4* dst = (f32x4*)(out + (size_t)pm * NPTS_C);
        __builtin_nontemporal_store(v, &dst[q]);
    }
}

// ---------------- FALLBACK (small ws) ----------------
__global__ void k_scatter_rank(const int4* __restrict__ coords, const uint2* __restrict__ combined,
                               int* __restrict__ origOf, int n) {
    int i = blockIdx.x * blockDim.x + threadIdx.x;
    if (i >= n) return;
    int4 co = coords[i];
    unsigned r = rank_of(make_key(co.x, co.y, co.z, co.w), combined);
    origOf[r] = i;
}

__device__ __forceinline__ int resolve_tap(int cb, int cx, int cy, int cz, int k,
                                           const uint2* __restrict__ combined) {
    int dx = k / 9 - 1, dy = (k % 9) / 3 - 1, dz = k % 3 - 1;
    int x = cx + dx, y = cy + dy, z = cz + dz;
    bool valid = (k < NTAPS) && ((unsigned)x < 256u) && ((unsigned)y < 256u) && ((unsigned)z < 256u);
    uint2 cw; cw.x = 0u; cw.y = 0u;
    if (k < 9) {
        int dxj = k / 3 - 1, dyj = k % 3 - 1;
        int xj = cx + dxj, yj = cy + dyj;
        if ((unsigned)xj < 256u && (unsigned)yj < 256u)
            cw = combined[make_key(cb, xj, yj, cz) >> 5];
    }
    int j = k / 3;
    unsigned bb = __shfl(cw.x, j, 32);
    unsigned pp = __shfl(cw.y, j, 32);
    int nidx = -1;
    if (valid) {
        unsigned keyk = make_key(cb, x, y, z);
        if ((z >> 5) != (cz >> 5)) {
            uint2 t2 = combined[keyk >> 5];
            bb = t2.x; pp = t2.y;
        }
        unsigned bit = keyk & 31u;
        if ((bb >> bit) & 1u)
            nidx = (int)(pp + __popc(bb & ((1u << bit) - 1u)));
    }
    return nidx;
}

__global__ __launch_bounds__(256) void k_conv_indirect(const float* __restrict__ feats, const float* __restrict__ weight,
                                                       const int4* __restrict__ coords,
                                                       const uint2* __restrict__ combined,
                                                       const int* __restrict__ origOf,
                                                       float* __restrict__ out, float* __restrict__ outCoordsF, int n) {
    __shared__ float swT[NTAPS * 32];
    for (int idx = threadIdx.x; idx < NTAPS * 32; idx += 256) {
        int kk = idx >> 5, cc = idx & 31;
        swT[idx] = weight[cc * NTAPS + kk];
    }
    __syncthreads();

    int p = blockIdx.x * 8 + (threadIdx.x >> 5);
    int c = threadIdx.x & 31;
    if (p >= n) return;

    int orig = origOf[p];
    int4 co = coords[orig];
    if (c == 0) {
        float4 f; f.x = (float)co.x; f.y = (float)co.y; f.z = (float)co.z; f.w = (float)co.w;
        ((float4*)outCoordsF)[p] = f;
    }

    int nidx0 = resolve_tap(co.x, co.y, co.z, co.w, c, combined);
    int nidx = (nidx0 >= 0) ? origOf[nidx0] : -1;

    unsigned long long full = __ballot(nidx >= 0);
    unsigned mymask = (threadIdx.x & 32) ? (unsigned)(full >> 32) : (unsigned)full;

    float acc = 0.0f;
    while (mymask) {
        int kk = __ffs(mymask) - 1;
        mymask &= mymask - 1;
        int g = __shfl(nidx, kk, 32);
        acc += feats[(size_t)g * NPTS_C + c] * swT[kk * 32 + c];
    }
    out[(size_t)p * NPTS_C + c] = acc;
}

extern "C" void kernel_launch(void* const* d_in, const int* in_sizes, int n_in,
                              void* d_out, int out_size, void* d_ws, size_t ws_size,
                              hipStream_t stream) {
    const float* feats  = (const float*)d_in[0];
    const int4*  coords = (const int4*)d_in[1];
    const float* weight = (const float*)d_in[2];
    const int n = in_sizes[1] / 4;

    float* out        = (float*)d_out;              // [N, 32] f32
    float* outCoordsF = (float*)d_out + n * NPTS_C; // [N, 4] float values

    char* ws = (char*)d_ws;
    unsigned* bitmask   = (unsigned*)ws;                               // 4 MB (reused as origOf in fallback)
    uint2*    combined  = (uint2*)(ws + (size_t)KEY_WORDS * 4);        // 8 MB
    unsigned* blockSums = (unsigned*)(ws + (size_t)KEY_WORDS * 12);    // 4 KB
    char*     rest      = ws + (size_t)KEY_WORDS * 12 + 4096;

    size_t need_big = (size_t)KEY_WORDS * 12 + 4096 + (size_t)n * NPTS_C * 4;
    bool big = ws_size >= need_big;

    (void)hipMemsetAsync(bitmask, 0, (size_t)KEY_WORDS * 4, stream);

    int tb = 256;
    k_scatter_bits<<<(n + tb - 1) / tb, tb, 0, stream>>>(coords, bitmask, n);
    k_popc_sums<<<SCAN_BLOCKS, 256, 0, stream>>>((const uint4*)bitmask, blockSums);
    k_build_combined<<<SCAN_BLOCKS, 256, 0, stream>>>((const uint4*)bitmask, blockSums, (uint4*)combined);

    if (big) {
        float* sfeats = (float*)rest; // N*32 f32 = 76.8 MB
        k_scatter_feats<<<((n * 8) + 255) / 256, 256, 0, stream>>>(feats, coords, combined,
                                                                   sfeats, outCoordsF, n);
        k_conv_sorted4<<<(n + 31) / 32, 256, 0, stream>>>(sfeats, weight, outCoordsF, combined, out, n);
    } else {
        int* origOf = (int*)bitmask; // bitmask dead after k_build_combined; N*4 <= 4 MB
        k_scatter_rank<<<(n + tb - 1) / tb, tb, 0, stream>>>(coords, combined, origOf, n);
        k_conv_indirect<<<(n + 7) / 8, 256, 0, stream>>>(feats, weight, coords, combined, origOf, out, outCoordsF, n);
    }
}

// Round 5
// 240.685 us; speedup vs baseline: 1.2314x; 1.0317x over previous
//
#include <hip/hip_runtime.h>

#define NPTS_C 32            // channels
#define NTAPS 27             // 3x3x3
#define KEY_WORDS (1u << 20) // 2^25 keys / 32 bits
#define SCAN_BLOCKS 1024     // KEY_WORDS / 1024 words per block

typedef float f32x4 __attribute__((ext_vector_type(4))); // native vec for nontemporal store

__device__ __forceinline__ unsigned make_key(int b, int x, int y, int z) {
    return ((((unsigned)b << 8 | (unsigned)x) << 8 | (unsigned)y) << 8) | (unsigned)z;
}

// 1) scatter occupancy bits
__global__ void k_scatter_bits(const int4* __restrict__ coords, unsigned* __restrict__ bitmask, int n) {
    int i = blockIdx.x * blockDim.x + threadIdx.x;
    if (i >= n) return;
    int4 co = coords[i];
    unsigned key = make_key(co.x, co.y, co.z, co.w);
    atomicOr(&bitmask[key >> 5], 1u << (key & 31u));
}

// 2) per-block (1024 words) popcount sums
__global__ void k_popc_sums(const uint4* __restrict__ bm4, unsigned* __restrict__ blockSums) {
    int t = threadIdx.x;
    uint4 w = bm4[blockIdx.x * 256 + t];
    unsigned s = __popc(w.x) + __popc(w.y) + __popc(w.z) + __popc(w.w);
    for (int off = 32; off > 0; off >>= 1) s += __shfl_down(s, off, 64);
    __shared__ unsigned wsum[4];
    if ((t & 63) == 0) wsum[t >> 6] = s;
    __syncthreads();
    if (t == 0) blockSums[blockIdx.x] = wsum[0] + wsum[1] + wsum[2] + wsum[3];
}

// 3) combined[word] = {bits, exclusive prefix popcount}
__global__ void k_build_combined(const uint4* __restrict__ bm4, const unsigned* __restrict__ blockSums,
                                 uint4* __restrict__ combined4) {
    int t = threadIdx.x, lane = t & 63;
    __shared__ unsigned preW[4];
    __shared__ unsigned wsum[4];

    unsigned pre = 0;
    for (int i = t; i < blockIdx.x; i += 256) pre += blockSums[i];
    for (int off = 32; off > 0; off >>= 1) pre += __shfl_down(pre, off, 64);
    if (lane == 0) preW[t >> 6] = pre;
    __syncthreads();
    unsigned blockBase = preW[0] + preW[1] + preW[2] + preW[3];

    int gw = blockIdx.x * 256 + t;
    uint4 w = bm4[gw];
    unsigned p0 = __popc(w.x), p1 = __popc(w.y), p2 = __popc(w.z), p3 = __popc(w.w);
    unsigned s = p0 + p1 + p2 + p3;
    unsigned incl = s;
    for (int off = 1; off < 64; off <<= 1) {
        unsigned u = __shfl_up(incl, off, 64);
        if (lane >= off) incl += u;
    }
    if (lane == 63) wsum[t >> 6] = incl;
    __syncthreads();
    unsigned waveBase = 0;
    int wv = t >> 6;
    for (int i = 0; i < wv; i++) waveBase += wsum[i];
    unsigned excl = blockBase + waveBase + incl - s;
    uint4 a; a.x = w.x; a.y = excl;           a.z = w.y; a.w = excl + p0;
    uint4 b; b.x = w.z; b.y = excl + p0 + p1; b.z = w.w; b.w = excl + p0 + p1 + p2;
    combined4[gw * 2 + 0] = a;
    combined4[gw * 2 + 1] = b;
}

__device__ __forceinline__ unsigned rank_of(unsigned key, const uint2* __restrict__ combined) {
    uint2 cw = combined[key >> 5];
    unsigned bit = key & 31u;
    return cw.y + __popc(cw.x & ((1u << bit) - 1u));
}

// 4) FUSED rank+gather, scatter-WRITE, 2 points/thread: two fully independent
//    coords->rank->write chains in flight per thread (round-4 lesson: one
//    dependent chain per thread leaves the wave idle for a full L2 round trip).
__global__ __launch_bounds__(256) void k_scatter_feats(const float* __restrict__ feats,
                                                       const int4* __restrict__ coords,
                                                       const uint2* __restrict__ combined,
                                                       float* __restrict__ sfeats,
                                                       float* __restrict__ outCoordsF, int n) {
    int q = threadIdx.x & 7;
    int i0 = blockIdx.x * 64 + (threadIdx.x >> 3); // first point
    int i1 = i0 + 32;                              // second point
    bool vA = i0 < n, vB = i1 < n;

    int4 coA, coB;
    float4 fA, fB;
    if (vA) coA = coords[i0];
    if (vB) coB = coords[i1];
    if (vA) fA = ((const float4*)(feats + (size_t)i0 * NPTS_C))[q]; // coalesced
    if (vB) fB = ((const float4*)(feats + (size_t)i1 * NPTS_C))[q]; // coalesced

    unsigned rA = 0, rB = 0;
    if (vA) rA = rank_of(make_key(coA.x, coA.y, coA.z, coA.w), combined);
    if (vB) rB = rank_of(make_key(coB.x, coB.y, coB.z, coB.w), combined);

    if (vA) {
        ((float4*)(sfeats + (size_t)rA * NPTS_C))[q] = fA;          // scattered full-row write
        if (q == 0) {
            float4 fc; fc.x = (float)coA.x; fc.y = (float)coA.y; fc.z = (float)coA.z; fc.w = (float)coA.w;
            ((float4*)outCoordsF)[rA] = fc;
        }
    }
    if (vB) {
        ((float4*)(sfeats + (size_t)rB * NPTS_C))[q] = fB;
        if (q == 0) {
            float4 fc; fc.x = (float)coB.x; fc.y = (float)coB.y; fc.z = (float)coB.z; fc.w = (float)coB.w;
            ((float4*)outCoordsF)[rB] = fc;
        }
    }
}

// 5) conv, phase-split resolve: issue ALL loads (4 coord reads, 4 primary
//    probes, conditional self-probes) before any consumption, so the emitted
//    code has ~2 serial memory latencies instead of ~4-8. VGPR budget: the
//    occupancy cliff is at 64 (waves halve at 64/128/256); the old version
//    used 12 -> ~50 regs of free MLP headroom. Center-tap row is prefetched
//    before __syncthreads so its latency hides under the barrier.
__global__ __launch_bounds__(256) void k_conv_sorted4(const float* __restrict__ sfeats,
                                                      const float* __restrict__ weight,
                                                      const float* __restrict__ outCoordsF,
                                                      const uint2* __restrict__ combined,
                                                      float* __restrict__ out, int n) {
    __shared__ float4 swT4[NTAPS * 9];   // swT4[kk*9+q] = weights for channels 4q..4q+3, tap kk (pad 8->9)
    __shared__ int ldsN[8][4][28];       // [group][round][tap] resolved sorted rank or -1

    int t = threadIdx.x;
    for (int idx = t; idx < NTAPS * 8; idx += 256) {
        int kk = idx >> 3, q = idx & 7;
        float4 w4;
        w4.x = weight[(4 * q + 0) * NTAPS + kk];
        w4.y = weight[(4 * q + 1) * NTAPS + kk];
        w4.z = weight[(4 * q + 2) * NTAPS + kk];
        w4.w = weight[(4 * q + 3) * NTAPS + kk];
        swT4[kk * 9 + q] = w4;
    }

    int gi = t >> 5, l = t & 31;
    bool hi = (t & 32) != 0;
    int p0 = (blockIdx.x * 8 + gi) * 4;  // 4 consecutive ranks per group
    int cluster = l >> 3, q = l & 7;

    // lane constants
    int dxl = l / 9 - 1, dyl = (l % 9) / 3 - 1, dzl = l % 3 - 1;
    int jl = l / 3;                      // probing lane for tap l
    int pbx = l / 3 - 1, pby = l % 3 - 1; // probe (dx,dy) for lanes 0..8

    // ---- Phase 1: all 4 rounds' coords — 4 independent broadcast loads ----
    int cbA[4], cxA[4], cyA[4], czA[4];
    #pragma unroll
    for (int r = 0; r < 4; r++) {
        int pc = min(p0 + r, n - 1);
        float4 cf = ((const float4*)outCoordsF)[pc]; // 4 rounds share one 64B line
        cbA[r] = (int)cf.x; cxA[r] = (int)cf.y; cyA[r] = (int)cf.z; czA[r] = (int)cf.w;
    }

    // ---- Phase 2a: primary probes for all 4 rounds (lanes 0..8) ----
    uint2 cwA[4];
    #pragma unroll
    for (int r = 0; r < 4; r++) {
        uint2 cw; cw.x = 0u; cw.y = 0u;
        if (l < 9) {
            int xj = cxA[r] + pbx, yj = cyA[r] + pby;
            if ((unsigned)xj < 256u && (unsigned)yj < 256u)
                cw = combined[make_key(cbA[r], xj, yj, czA[r]) >> 5];
        }
        cwA[r] = cw;
    }

    // ---- Phase 2b: conditional self-probes (z crossed word boundary) ----
    uint2 spA[4];
    #pragma unroll
    for (int r = 0; r < 4; r++) {
        int x = cxA[r] + dxl, y = cyA[r] + dyl, z = czA[r] + dzl;
        bool ok = (l < NTAPS) && (l != 13) &&
                  (unsigned)x < 256u && (unsigned)y < 256u && (unsigned)z < 256u;
        bool sp = ok && ((z >> 5) != (czA[r] >> 5));
        uint2 t2; t2.x = 0u; t2.y = 0u;
        if (sp) t2 = combined[make_key(cbA[r], x, y, z) >> 5];
        spA[r] = t2;
    }

    // ---- center-tap prefetch: latency hides under phase 3 + barrier ----
    int pm = p0 + cluster;
    float4 fc_c; fc_c.x = fc_c.y = fc_c.z = fc_c.w = 0.0f;
    if (pm < n) fc_c = ((const float4*)(sfeats + (size_t)pm * NPTS_C))[q];

    // ---- Phase 3: pure ALU/shuffle/ballot/LDS (no new memory latency) ----
    unsigned mk[4];
    #pragma unroll
    for (int r = 0; r < 4; r++) {
        unsigned bb = __shfl(cwA[r].x, jl, 32);
        unsigned pp = __shfl(cwA[r].y, jl, 32);
        int x = cxA[r] + dxl, y = cyA[r] + dyl, z = czA[r] + dzl;
        bool ok = (l < NTAPS) && (l != 13) &&
                  (unsigned)x < 256u && (unsigned)y < 256u && (unsigned)z < 256u;
        bool sp = ok && ((z >> 5) != (czA[r] >> 5));
        if (sp) { bb = spA[r].x; pp = spA[r].y; }
        int nidx = -1;
        if (ok) {
            unsigned keyk = make_key(cbA[r], x, y, z);
            unsigned bit = keyk & 31u;
            if ((bb >> bit) & 1u)
                nidx = (int)(pp + __popc(bb & ((1u << bit) - 1u)));
        }
        unsigned long long bal = __ballot(nidx >= 0);
        mk[r] = hi ? (unsigned)(bal >> 32) : (unsigned)bal;
        if (l < NTAPS) ldsN[gi][r][l] = nidx;
    }
    __syncthreads(); // covers swT4 fill + ldsN writes

    float4 acc; acc.x = acc.y = acc.z = acc.w = 0.0f;
    if (pm < n) { // center tap from prefetched row
        float4 w4 = swT4[13 * 9 + q];
        acc.x = fc_c.x * w4.x; acc.y = fc_c.y * w4.y; acc.z = fc_c.z * w4.z; acc.w = fc_c.w * w4.w;
    }

    unsigned m = mk[cluster]; // cluster-uniform mask, ~0.47 set bits avg
    while (m) {
        int kk = __ffs(m) - 1; m &= m - 1;
        int g = ldsN[gi][cluster][kk];                        // broadcast ds_read
        float4 f = ((const float4*)(sfeats + (size_t)g * NPTS_C))[q]; // rank-local 128B row
        float4 w4 = swT4[kk * 9 + q];
        acc.x += f.x * w4.x; acc.y += f.y * w4.y; acc.z += f.z * w4.z; acc.w += f.w * w4.w;
    }
    if (pm < n) {
        f32x4 v; v.x = acc.x; v.y = acc.y; v.z = acc.z; v.w = acc.w;
        f32x4* dst = (f32x4*)(out + (size_t)pm * NPTS_C);
        __builtin_nontemporal_store(v, &dst[q]);
    }
}

// ---------------- FALLBACK (small ws) ----------------
__global__ void k_scatter_rank(const int4* __restrict__ coords, const uint2* __restrict__ combined,
                               int* __restrict__ origOf, int n) {
    int i = blockIdx.x * blockDim.x + threadIdx.x;
    if (i >= n) return;
    int4 co = coords[i];
    unsigned r = rank_of(make_key(co.x, co.y, co.z, co.w), combined);
    origOf[r] = i;
}

__device__ __forceinline__ int resolve_tap(int cb, int cx, int cy, int cz, int k,
                                           const uint2* __restrict__ combined) {
    int dx = k / 9 - 1, dy = (k % 9) / 3 - 1, dz = k % 3 - 1;
    int x = cx + dx, y = cy + dy, z = cz + dz;
    bool valid = (k < NTAPS) && ((unsigned)x < 256u) && ((unsigned)y < 256u) && ((unsigned)z < 256u);
    uint2 cw; cw.x = 0u; cw.y = 0u;
    if (k < 9) {
        int dxj = k / 3 - 1, dyj = k % 3 - 1;
        int xj = cx + dxj, yj = cy + dyj;
        if ((unsigned)xj < 256u && (unsigned)yj < 256u)
            cw = combined[make_key(cb, xj, yj, cz) >> 5];
    }
    int j = k / 3;
    unsigned bb = __shfl(cw.x, j, 32);
    unsigned pp = __shfl(cw.y, j, 32);
    int nidx = -1;
    if (valid) {
        unsigned keyk = make_key(cb, x, y, z);
        if ((z >> 5) != (cz >> 5)) {
            uint2 t2 = combined[keyk >> 5];
            bb = t2.x; pp = t2.y;
        }
        unsigned bit = keyk & 31u;
        if ((bb >> bit) & 1u)
            nidx = (int)(pp + __popc(bb & ((1u << bit) - 1u)));
    }
    return nidx;
}

__global__ __launch_bounds__(256) void k_conv_indirect(const float* __restrict__ feats, const float* __restrict__ weight,
                                                       const int4* __restrict__ coords,
                                                       const uint2* __restrict__ combined,
                                                       const int* __restrict__ origOf,
                                                       float* __restrict__ out, float* __restrict__ outCoordsF, int n) {
    __shared__ float swT[NTAPS * 32];
    for (int idx = threadIdx.x; idx < NTAPS * 32; idx += 256) {
        int kk = idx >> 5, cc = idx & 31;
        swT[idx] = weight[cc * NTAPS + kk];
    }
    __syncthreads();

    int p = blockIdx.x * 8 + (threadIdx.x >> 5);
    int c = threadIdx.x & 31;
    if (p >= n) return;

    int orig = origOf[p];
    int4 co = coords[orig];
    if (c == 0) {
        float4 f; f.x = (float)co.x; f.y = (float)co.y; f.z = (float)co.z; f.w = (float)co.w;
        ((float4*)outCoordsF)[p] = f;
    }

    int nidx0 = resolve_tap(co.x, co.y, co.z, co.w, c, combined);
    int nidx = (nidx0 >= 0) ? origOf[nidx0] : -1;

    unsigned long long full = __ballot(nidx >= 0);
    unsigned mymask = (threadIdx.x & 32) ? (unsigned)(full >> 32) : (unsigned)full;

    float acc = 0.0f;
    while (mymask) {
        int kk = __ffs(mymask) - 1;
        mymask &= mymask - 1;
        int g = __shfl(nidx, kk, 32);
        acc += feats[(size_t)g * NPTS_C + c] * swT[kk * 32 + c];
    }
    out[(size_t)p * NPTS_C + c] = acc;
}

extern "C" void kernel_launch(void* const* d_in, const int* in_sizes, int n_in,
                              void* d_out, int out_size, void* d_ws, size_t ws_size,
                              hipStream_t stream) {
    const float* feats  = (const float*)d_in[0];
    const int4*  coords = (const int4*)d_in[1];
    const float* weight = (const float*)d_in[2];
    const int n = in_sizes[1] / 4;

    float* out        = (float*)d_out;              // [N, 32] f32
    float* outCoordsF = (float*)d_out + n * NPTS_C; // [N, 4] float values

    char* ws = (char*)d_ws;
    unsigned* bitmask   = (unsigned*)ws;                               // 4 MB (reused as origOf in fallback)
    uint2*    combined  = (uint2*)(ws + (size_t)KEY_WORDS * 4);        // 8 MB
    unsigned* blockSums = (unsigned*)(ws + (size_t)KEY_WORDS * 12);    // 4 KB
    char*     rest      = ws + (size_t)KEY_WORDS * 12 + 4096;

    size_t need_big = (size_t)KEY_WORDS * 12 + 4096 + (size_t)n * NPTS_C * 4;
    bool big = ws_size >= need_big;

    (void)hipMemsetAsync(bitmask, 0, (size_t)KEY_WORDS * 4, stream);

    int tb = 256;
    k_scatter_bits<<<(n + tb - 1) / tb, tb, 0, stream>>>(coords, bitmask, n);
    k_popc_sums<<<SCAN_BLOCKS, 256, 0, stream>>>((const uint4*)bitmask, blockSums);
    k_build_combined<<<SCAN_BLOCKS, 256, 0, stream>>>((const uint4*)bitmask, blockSums, (uint4*)combined);

    if (big) {
        float* sfeats = (float*)rest; // N*32 f32 = 76.8 MB
        k_scatter_feats<<<(n + 63) / 64, 256, 0, stream>>>(feats, coords, combined,
                                                           sfeats, outCoordsF, n);
        k_conv_sorted4<<<(n + 31) / 32, 256, 0, stream>>>(sfeats, weight, outCoordsF, combined, out, n);
    } else {
        int* origOf = (int*)bitmask; // bitmask dead after k_build_combined; N*4 <= 4 MB
        k_scatter_rank<<<(n + tb - 1) / tb, tb, 0, stream>>>(coords, combined, origOf, n);
        k_conv_indirect<<<(n + 7) / 8, 256, 0, stream>>>(feats, weight, coords, combined, origOf, out, outCoordsF, n);
    }
}